// Round 12
// baseline (663.828 us; speedup 1.0000x reference)
//
#include <hip/hip_runtime.h>
#include <hip/hip_bf16.h>
#include <math.h>

// Problem constants
#define BGR 8        // graphs
#define PP 4096      // points per graph
#define NPTS 32768   // B*P
#define KNN 20
#define LCOV 10
#define FF 32
#define KS 5
#define NCLS 40
#define NGROUP 24    // 3*B, rows of ys
#define GROUPLEN 131072  // P*F flat elements per group

// KNN tiling: 256 blocks x 1024 threads; thread = (eighth 0..7, pt 0..127)
#define SPLIT 8
#define CHUNK (PP / SPLIT)        // 512 candidates per thread
#define PTSBLK 128                // points per block
#define KTHR 1024
#define CAP 7                     // shift-register depth: 3 carry + 4/window
#define NSLOT (KNN + 1)           // 21-slot network (self-point absorbable)
#define MPAD NSLOT                // merge-list stride 21: gcd(21,32)=1
#define SENT 0xFFFFFFFFu

// ---------------------------------------------------------------------------
// Kernel 1: brute-force KNN + folded eigen stage. Scan path = R11 (proven).
// R12 delta: neighbor lists stored as u16 graph-local indices (nbr16).
// ---------------------------------------------------------------------------
__device__ inline unsigned umn(unsigned a, unsigned b) { return a < b ? a : b; }
__device__ inline unsigned umx(unsigned a, unsigned b) { return a > b ? a : b; }

__device__ inline void mat3vec(const float M[9], const float v[3], float w[3]) {
    w[0] = M[0] * v[0] + M[1] * v[1] + M[2] * v[2];
    w[1] = M[3] * v[0] + M[4] * v[1] + M[5] * v[2];
    w[2] = M[6] * v[0] + M[7] * v[1] + M[8] * v[2];
}

__device__ inline float pi3(const float M[9], float v[3]) {
    v[0] = v[1] = v[2] = 0.57735026918962576f;  // 3^-0.5 as f32
#pragma unroll
    for (int it = 0; it < 5; ++it) {
        float w[3];
        mat3vec(M, v, w);
        float nrm = sqrtf(w[0] * w[0] + w[1] * w[1] + w[2] * w[2]) + 1e-12f;
        v[0] = w[0] / nrm;
        v[1] = w[1] / nrm;
        v[2] = w[2] / nrm;
    }
    float w[3];
    mat3vec(M, v, w);
    return v[0] * w[0] + v[1] * w[1] + v[2] * w[2];
}

__global__ __launch_bounds__(KTHR, 8) void knn_kernel(
    const float* __restrict__ pos, unsigned short* __restrict__ nbr16,
    float* __restrict__ Rbuf, float* __restrict__ v3out) {
    __shared__ float smem[4 * PP];   // 64 KB arena
    float* tx = smem;                // scan: -2x  | post-merge: raw x
    float* ty = smem + PP;           // scan: -2y  | post-merge: raw y
    float* tz = smem + 2 * PP;       // scan: -2z  | post-merge: raw z
    float* tw = smem + 3 * PP;       // scan: |q|^2 (dead after scan)
    unsigned short* lnbr = (unsigned short*)(smem + 3 * PP + 2816);

    int b = blockIdx.x >> 5;          // 32 blocks per graph
    int blkInGraph = blockIdx.x & 31;
    const float* gp = pos + (size_t)b * PP * 3;
    for (int i = threadIdx.x; i < PP; i += KTHR) {
        float x = gp[i * 3 + 0];
        float y = gp[i * 3 + 1];
        float z = gp[i * 3 + 2];
        tx[i] = -2.0f * x;
        ty[i] = -2.0f * y;
        tz[i] = -2.0f * z;
        tw[i] = x * x + y * y + z * z;
    }
    __syncthreads();

    int eighth = threadIdx.x >> 7;        // 0..7 (wave-uniform)
    int pt = threadIdx.x & (PTSBLK - 1);  // 0..127
    int li = blkInGraph * PTSBLK + pt;    // local point index in graph
    float px = -0.5f * tx[li];
    float py = -0.5f * ty[li];
    float pz = -0.5f * tz[li];
    float p2 = tw[li];

    unsigned bd[NSLOT];
#pragma unroll
    for (int k = 0; k < NSLOT; k++) bd[k] = SENT;
    float worst_hat = INFINITY;

    unsigned bufk[CAP];
#pragma unroll
    for (int s = 0; s < CAP; s++) bufk[s] = SENT;

    auto flush = [&]() {
#pragma unroll
        for (int s = 0; s < CAP; s++) {
            if (!__any(bufk[s] != SENT)) break;   // monotone: FIFO fills 0..
            unsigned k = bufk[s];
#pragma unroll
            for (int i = 0; i < NSLOT; i++) {
                unsigned lo = umn(k, bd[i]);   // v_min_u32
                k = umx(k, bd[i]);             // v_max_u32
                bd[i] = lo;
            }
            bufk[s] = SENT;
        }
        unsigned wb = bd[NSLOT - 1];
        worst_hat = (wb == SENT) ? INFINITY
                                 : __uint_as_float(wb & 0xFFFFF000u) - p2;
    };

    int jbeg = eighth * CHUNK;
    for (int jj = jbeg; jj < jbeg + CHUNK; jj += 4) {
        float4 xv = *(const float4*)(tx + jj);
        float4 yv = *(const float4*)(ty + jj);
        float4 zv = *(const float4*)(tz + jj);
        float4 wv = *(const float4*)(tw + jj);
        float xa[4] = {xv.x, xv.y, xv.z, xv.w};
        float ya[4] = {yv.x, yv.y, yv.z, yv.w};
        float za[4] = {zv.x, zv.y, zv.z, zv.w};
        float wa[4] = {wv.x, wv.y, wv.z, wv.w};
#pragma unroll
        for (int u = 0; u < 4; u++) {
            float dh = fmaf(px, xa[u], fmaf(py, ya[u], fmaf(pz, za[u], wa[u])));
            if (dh < worst_hat) {
                float d = fmaxf(dh + p2, 0.0f);
                unsigned key = (__float_as_uint(d) & 0xFFFFF000u)
                               | (unsigned)(jj + u);
                bufk[6] = bufk[5];
                bufk[5] = bufk[4];
                bufk[4] = bufk[3];
                bufk[3] = bufk[2];
                bufk[2] = bufk[1];
                bufk[1] = bufk[0];
                bufk[0] = key;
            }
        }
        if (__any(bufk[3] != SENT)) flush();
    }
    flush();

    // ---- 8-way merge, two 64-point phases; emits global nbr16 + LDS lnbr ---
    __syncthreads();
    unsigned* mk = (unsigned*)smem;    // words 0..10751
    for (int h = 0; h < 2; h++) {
        if ((pt >> 6) == h) {
            int lpt = pt & 63;
#pragma unroll
            for (int k = 0; k < NSLOT; k++)
                mk[(eighth * 64 + lpt) * MPAD + k] = bd[k];
        }
        __syncthreads();
        if (threadIdx.x < 64) {
            int p = threadIdx.x;
            const unsigned* base = &mk[p * MPAD];
            int cur[SPLIT];
#pragma unroll
            for (int q = 0; q < SPLIT; q++) cur[q] = 0;
            int lpt2 = h * 64 + p;
            int gi = b * PP + blkInGraph * PTSBLK + lpt2;
#pragma unroll
            for (int t = 0; t < NSLOT; t++) {
                unsigned v[SPLIT];
#pragma unroll
                for (int q = 0; q < SPLIT; q++)
                    v[q] = base[q * 64 * MPAD + cur[q]];
                unsigned m = v[0];
#pragma unroll
                for (int q = 1; q < SPLIT; q++) m = umn(m, v[q]);
                if (t > 0) {
                    int local = (int)(m & 0xFFFu);
                    nbr16[(size_t)gi * KNN + (t - 1)] = (unsigned short)local;
                    lnbr[lpt2 * KNN + (t - 1)] = (unsigned short)local;
                }
#pragma unroll
                for (int q = 0; q < SPLIT; q++) cur[q] += (v[q] == m);
            }
        }
        __syncthreads();
    }

    // ---- re-stage RAW coords (L2-hot) for the eig tail ----
    for (int i = threadIdx.x; i < PP; i += KTHR) {
        tx[i] = gp[i * 3 + 0];
        ty[i] = gp[i * 3 + 1];
        tz[i] = gp[i * 3 + 2];
    }
    __syncthreads();

    // ---- eig tail: threads 0..127, one point each, all data in LDS ----
    if (threadIdx.x < PTSBLK) {
        int lp = threadIdx.x;
        int ng = blkInGraph * PTSBLK + lp;
        int n = b * PP + ng;
        float qx = tx[ng], qy = ty[ng], qz = tz[ng];
        const unsigned short* ln = &lnbr[lp * KNN];

        float m00 = 0.f, m01 = 0.f, m02 = 0.f, m11 = 0.f, m12 = 0.f, m22 = 0.f;
#pragma unroll
        for (int k = 0; k < LCOV; k++) {
            int id = ln[k];
            float cx = tx[id] - qx;
            float cy = ty[id] - qy;
            float cz = tz[id] - qz;
            m00 += cx * cx; m01 += cx * cy; m02 += cx * cz;
            m11 += cy * cy; m12 += cy * cz; m22 += cz * cz;
        }
        float M[9] = {m00, m01, m02, m01, m11, m12, m02, m12, m22};

        float v1[3], v2[3], v3[3];
        float l1 = pi3(M, v1);
        float M2[9];
#pragma unroll
        for (int c = 0; c < 3; c++)
#pragma unroll
            for (int d = 0; d < 3; d++)
                M2[c * 3 + d] = M[c * 3 + d] - l1 * v1[c] * v1[d];
        pi3(M2, v2);
        v3[0] = v1[1] * v2[2] - v1[2] * v2[1];
        v3[1] = v1[2] * v2[0] - v1[0] * v2[2];
        v3[2] = v1[0] * v2[1] - v1[1] * v2[0];
        {
            float nrm = sqrtf(v3[0] * v3[0] + v3[1] * v3[1] + v3[2] * v3[2]) + 1e-12f;
            v3[0] /= nrm; v3[1] /= nrm; v3[2] /= nrm;
        }

        float ssum = 0.f, mx = 0.f;
#pragma unroll
        for (int k = 0; k < KNN; k++) {
            int id = ln[k];
            float cx = tx[id] - qx;
            float cy = ty[id] - qy;
            float cz = tz[id] - qz;
            float d0 = cx * v1[0] + cy * v1[1] + cz * v1[2];
            float d1 = cx * v2[0] + cy * v2[1] + cz * v2[2];
            float d2 = cx * v3[0] + cy * v3[1] + cz * v3[2];
            ssum += d2;
            mx = fmaxf(mx, fabsf(d0));
            mx = fmaxf(mx, fabsf(d1));
            mx = fmaxf(mx, fabsf(d2));
        }
        float sgn = (ssum > 0.f) ? 1.f : ((ssum < 0.f) ? -1.f : 0.f);

        float sc = 2.0f / mx;
        float* R = Rbuf + (size_t)n * 12;
        R[0] = v1[0] * sc;  R[1] = v1[1] * sc;  R[2] = v1[2] * sc;
        R[3] = v2[0] * sc;  R[4] = v2[1] * sc;  R[5] = v2[2] * sc;
        float s2 = sgn * sc;
        R[6] = v3[0] * s2;  R[7] = v3[1] * s2;  R[8] = v3[2] * s2;
        R[9] = 0.f; R[10] = 0.f; R[11] = 0.f;

        v3out[n * 3 + 0] = v3[0];
        v3out[n * 3 + 1] = v3[1];
        v3out[n * 3 + 2] = v3[2];
    }
}

// ---------------------------------------------------------------------------
// Kernel 2: spline conv + FUSED bn statistics.
// Each block reduces its own 16x32 node chunk to a 64-wide partial (sum |
// sumsq) in sums_part; the LAST block (device-scope atomic counter +
// __threadfence, per G16) reduces all 2048 partials to stats[64].
// Replaces the standalone bn_stats kernel.
// ---------------------------------------------------------------------------
#define NPB 16
#define SPLBLKS (NPTS / NPB)   // 2048
__global__ __launch_bounds__(512) void spline_kernel(
    const float* __restrict__ pos, const unsigned short* __restrict__ nbr16,
    const float* __restrict__ Rbuf, const float* __restrict__ Wsp,
    const float* __restrict__ root, const float* __restrict__ bias,
    float* __restrict__ node, float* __restrict__ sums_part,
    float* __restrict__ stats_g, int* __restrict__ counter) {
    __shared__ float sWt[FF * 125];          // [f][flat]
    __shared__ float wbuf[NPB * KNN * 8];    // packed w' per (pt,k,s); reused
    __shared__ int isLast;
    for (int i = threadIdx.x; i < FF * 125; i += 512) {
        int f = i / 125;
        int j = i - f * 125;
        sWt[i] = Wsp[j * FF + f];
    }

    int tid = threadIdx.x;
    if (tid < NPB * KNN) {              // 320 phase-1 threads
        int pt = tid / KNN;
        int k = tid - pt * KNN;
        int n = blockIdx.x * NPB + pt;
        const float4* Rv = (const float4*)(Rbuf + (size_t)n * 12);
        float4 r0 = Rv[0], r1 = Rv[1], r2 = Rv[2];
        float px = pos[n * 3 + 0], py = pos[n * 3 + 1], pz = pos[n * 3 + 2];
        int id = (n & ~(PP - 1)) | (int)nbr16[(size_t)n * KNN + k];
        float cxx = pos[id * 3 + 0] - px;
        float cyy = pos[id * 3 + 1] - py;
        float czz = pos[id * 3 + 2] - pz;
        float v0 = fmaf(cxx, r0.x, fmaf(cyy, r0.y, fmaf(czz, r0.z, 2.0f)));
        float v1 = fmaf(cxx, r0.w, fmaf(cyy, r1.x, fmaf(czz, r1.y, 2.0f)));
        float v2 = fmaf(cxx, r1.z, fmaf(cyy, r1.w, fmaf(czz, r2.x, 2.0f)));
        float f0 = floorf(v0), f1 = floorf(v1), f2 = floorf(v2);
        float fr0 = v0 - f0, fr1 = v1 - f1, fr2 = v2 - f2;
        int fi0 = (int)f0, fi1 = (int)f1, fi2 = (int)f2;
        float* wdst = &wbuf[(pt * KNN + k) * 8];
#pragma unroll
        for (int s = 0; s < 8; s++) {
            int b0 = (s >> 2) & 1, b1 = (s >> 1) & 1, b2s = s & 1;
            int i0 = min(max(fi0 + b0, 0), KS - 1);
            int i1 = min(max(fi1 + b1, 0), KS - 1);
            int i2 = min(max(fi2 + b2s, 0), KS - 1);
            float w = (b0 ? fr0 : 1.f - fr0) * (b1 ? fr1 : 1.f - fr1) *
                      (b2s ? fr2 : 1.f - fr2);
            unsigned flat = (unsigned)((i0 * KS + i1) * KS + i2);
            wdst[s] = __uint_as_float((__float_as_uint(w) & ~127u) | flat);
        }
    }
    __syncthreads();

    // phase 2: thread = (pt, f)
    int pt = tid >> 5;
    int f = tid & 31;
    const float* wrow = &wbuf[pt * (KNN * 8)];
    const float* srow = &sWt[f * 125];
    float acc = 0.f;
#pragma unroll
    for (int k = 0; k < KNN; k++) {
        float4 wa = *(const float4*)&wrow[k * 8];
        float4 wb = *(const float4*)&wrow[k * 8 + 4];
        float wv[8] = {wa.x, wa.y, wa.z, wa.w, wb.x, wb.y, wb.z, wb.w};
#pragma unroll
        for (int s = 0; s < 8; s++) {
            unsigned u = __float_as_uint(wv[s]) & 127u;
            acc = fmaf(wv[s], srow[u], acc);
        }
    }
    int n = blockIdx.x * NPB + pt;
    float val = acc * (1.0f / KNN) + root[f] + bias[f];
    node[(size_t)n * FF + f] = val;

    // ---- fused bn partial: reduce this block's 512 values to 64 ----
    __syncthreads();                 // wbuf reads done; safe to reuse
    wbuf[tid] = val;
    wbuf[512 + tid] = val * val;
    __syncthreads();
    if (tid < 64) {
        int ff = tid & 31;
        int off = (tid >> 5) * 512;  // 0 = sum, 512 = sumsq
        float s = 0.f;
#pragma unroll
        for (int p = 0; p < NPB; p++) s += wbuf[off + p * 32 + ff];
        sums_part[(size_t)blockIdx.x * 64 + (tid >> 5) * 32 + ff] = s;
    }
    __threadfence();                 // release partials (device scope)
    if (tid == 0) {
        int old = atomicAdd(counter, 1);
        isLast = (old == SPLBLKS - 1);
    }
    __syncthreads();
    if (isLast) {
        __threadfence();             // acquire all partials
        if (tid < 256) {
            int col = tid & 63, q = tid >> 6;
            float s = 0.f;
            for (int p = q; p < SPLBLKS; p += 4) s += sums_part[p * 64 + col];
            wbuf[tid] = s;
        }
        __syncthreads();
        if (tid < 64)
            stats_g[tid] = wbuf[tid] + wbuf[64 + tid] + wbuf[128 + tid] +
                           wbuf[192 + tid];
    }
}

// ---------------------------------------------------------------------------
// Kernel 3: BN apply + sigmoid + reduce to ys partials; the LAST block also
// runs the whole MLP head + log_softmax (replaces head_kernel).
// ---------------------------------------------------------------------------
#define YSPLIT 8
#define YBLKS (NGROUP * YSPLIT)      // 192
#define YCHUNK (GROUPLEN / YSPLIT)   // 16384
__global__ __launch_bounds__(256) void ys_kernel(
    const float* __restrict__ node, const float* __restrict__ v3,
    const float* __restrict__ stats_g, const float* __restrict__ gamma,
    const float* __restrict__ beta, float* __restrict__ ys_part,
    const float* __restrict__ W1, const float* __restrict__ b1,
    const float* __restrict__ W2, const float* __restrict__ b2,
    float* __restrict__ out, int* __restrict__ counter) {
    __shared__ float sa[FF], sb[FF];
    __shared__ float red[256];
    __shared__ int isLast;
    if (threadIdx.x < FF) {
        int f = threadIdx.x;
        float mu = stats_g[f] * (1.0f / NPTS);
        float var = stats_g[FF + f] * (1.0f / NPTS) - mu * mu;
        float inv = 1.0f / sqrtf(var + 1e-5f);
        sa[f] = gamma[f] * inv;
        sb[f] = beta[f] - gamma[f] * inv * mu;
    }
    __syncthreads();

    int g = blockIdx.x >> 3;
    int sub = blockIdx.x & 7;
    int t0 = g * GROUPLEN + sub * YCHUNK + threadIdx.x;
    int n = t0 / 96;
    int r0 = t0 - n * 96;
    int rj[3], fj[3], cj[3], dj[3];
    rj[0] = r0;
    rj[1] = (r0 + 64) % 96;
    rj[2] = (r0 + 32) % 96;
#pragma unroll
    for (int j = 0; j < 3; j++) {
        fj[j] = rj[j] / 3;
        cj[j] = rj[j] - fj[j] * 3;
        dj[j] = (rj[j] >= 32) ? 3 : 2;
    }
    float Sa0 = sa[fj[0]], Sb0 = sb[fj[0]];
    float Sa1 = sa[fj[1]], Sb1 = sb[fj[1]];
    float Sa2 = sa[fj[2]], Sb2 = sb[fj[2]];
    int nf = n * FF;
    int n3 = n * 3;

    float acc = 0.f;
#pragma unroll 1
    for (int tr = 0; tr < 21; tr++) {
        {
            float xb = fmaf(Sa0, node[nf + fj[0]], Sb0);
            float val = xb * v3[n3 + cj[0]];
            acc += 1.0f / (1.0f + __expf(-val));
            nf += dj[0] * FF; n3 += dj[0] * 3;
        }
        {
            float xb = fmaf(Sa1, node[nf + fj[1]], Sb1);
            float val = xb * v3[n3 + cj[1]];
            acc += 1.0f / (1.0f + __expf(-val));
            nf += dj[1] * FF; n3 += dj[1] * 3;
        }
        {
            float xb = fmaf(Sa2, node[nf + fj[2]], Sb2);
            float val = xb * v3[n3 + cj[2]];
            acc += 1.0f / (1.0f + __expf(-val));
            nf += dj[2] * FF; n3 += dj[2] * 3;
        }
    }
    {
        float xb = fmaf(Sa0, node[nf + fj[0]], Sb0);
        float val = xb * v3[n3 + cj[0]];
        acc += 1.0f / (1.0f + __expf(-val));
    }

    red[threadIdx.x] = acc;
    __syncthreads();
    if (threadIdx.x < FF) {
        float s = 0.f;
        for (int t = threadIdx.x; t < 256; t += FF) s += red[t];
        ys_part[(sub * NGROUP + g) * FF + threadIdx.x] = s * (1.0f / PP);
    }
    __threadfence();                 // release ys partials
    if (threadIdx.x == 0) {
        int old = atomicAdd(counter, 1);
        isLast = (old == YBLKS - 1);
    }
    __syncthreads();
    if (!isLast) return;
    __threadfence();                 // acquire all ys partials

    // ---- MLP head on the last block ----
    __shared__ float syr[NGROUP * FF];        // 768
    __shared__ float hbuf[NGROUP * 256];      // 6144 (24 KB)
    __shared__ float logitsb[NGROUP * NCLS];  // 960
    __shared__ float mmv[NGROUP], llv[NGROUP];
    int tid = threadIdx.x;
    for (int idx = tid; idx < NGROUP * FF; idx += 256) {
        int gg = idx >> 5, ff = idx & 31;
        float s = 0.f;
#pragma unroll
        for (int s2 = 0; s2 < YSPLIT; s2++)
            s += ys_part[(s2 * NGROUP + gg) * FF + ff];
        syr[idx] = s;
    }
    __syncthreads();
    {
        int j = tid;
        for (int gg = 0; gg < NGROUP; gg++) {
            float a = b1[j];
#pragma unroll
            for (int ff = 0; ff < FF; ff++)
                a = fmaf(syr[gg * FF + ff], W1[ff * 256 + j], a);
            hbuf[gg * 256 + j] = a > 0.f ? a : expm1f(a);
        }
    }
    __syncthreads();
    for (int idx = tid; idx < NGROUP * NCLS; idx += 256) {
        int gg = idx / NCLS, o = idx - gg * NCLS;
        float l = b2[o];
        for (int q = 0; q < 256; q++)
            l = fmaf(hbuf[gg * 256 + q], W2[q * NCLS + o], l);
        logitsb[idx] = l;
    }
    __syncthreads();
    if (tid < NGROUP) {
        float m = -INFINITY;
        for (int o = 0; o < NCLS; o++) m = fmaxf(m, logitsb[tid * NCLS + o]);
        float s = 0.f;
        for (int o = 0; o < NCLS; o++) s += expf(logitsb[tid * NCLS + o] - m);
        mmv[tid] = m;
        llv[tid] = logf(s);
    }
    __syncthreads();
    for (int idx = tid; idx < NGROUP * NCLS; idx += 256) {
        int gg = idx / NCLS;
        out[idx] = logitsb[idx] - mmv[gg] - llv[gg];
    }
}

// ---------------------------------------------------------------------------
extern "C" void kernel_launch(void* const* d_in, const int* in_sizes, int n_in,
                              void* d_out, int out_size, void* d_ws, size_t ws_size,
                              hipStream_t stream) {
    const float* pos   = (const float*)d_in[0];
    const float* Wsp   = (const float*)d_in[1];
    const float* root  = (const float*)d_in[2];
    const float* bias  = (const float*)d_in[3];
    const float* gamma = (const float*)d_in[4];
    const float* beta  = (const float*)d_in[5];
    const float* W1    = (const float*)d_in[6];
    const float* b1    = (const float*)d_in[7];
    const float* W2    = (const float*)d_in[8];
    const float* b2    = (const float*)d_in[9];
    float* out = (float*)d_out;

    char* ws = (char*)d_ws;
    // layout (unchanged total footprint ~8.79 MB):
    unsigned short* nbr16 = (unsigned short*)(ws);     // 32768*20*2 = 1310720
    float* sums_part = (float*)(ws + 1310720);         // 2048*64*4  = 524288
    float* stats_g   = (float*)(ws + 1835008);         // 64*4       = 256
    int*   counters  = (int*)(ws + 1835264);           // 2 ints (16 B pad)
    float* ys_part   = (float*)(ws + 1835392);         // 8*24*32*4  = 24576
    float* node = (float*)(ws + 2621440);              // 32768*32*4 = 4194304
    float* v3   = (float*)(ws + 6815744);              // 32768*3*4  = 393216
    float* Rbuf = (float*)(ws + 7212288);              // 32768*12*4 = 1572864

    hipMemsetAsync(counters, 0, 16, stream);

    knn_kernel<<<256, KTHR, 0, stream>>>(pos, nbr16, Rbuf, v3);
    spline_kernel<<<SPLBLKS, 512, 0, stream>>>(pos, nbr16, Rbuf, Wsp, root, bias,
                                               node, sums_part, stats_g,
                                               &counters[0]);
    ys_kernel<<<YBLKS, 256, 0, stream>>>(node, v3, stats_g, gamma, beta, ys_part,
                                         W1, b1, W2, b2, out, &counters[1]);
}

// Round 13
// 274.933 us; speedup vs baseline: 2.4145x; 2.4145x over previous
//
#include <hip/hip_runtime.h>
#include <hip/hip_bf16.h>
#include <math.h>

// Problem constants
#define BGR 8        // graphs
#define PP 4096      // points per graph
#define NPTS 32768   // B*P
#define KNN 20
#define LCOV 10
#define FF 32
#define KS 5
#define NCLS 40
#define NGROUP 24    // 3*B, rows of ys
#define GROUPLEN 131072  // P*F flat elements per group

// KNN tiling: 256 blocks x 1024 threads; thread = (eighth 0..7, pt 0..127)
#define SPLIT 8
#define CHUNK (PP / SPLIT)        // 512 candidates per thread
#define PTSBLK 128                // points per block
#define KTHR 1024
#define CAP 7                     // shift-register depth: 3 carry + 4/window
#define NSLOT (KNN + 1)           // 21-slot network (self-point absorbable)
#define MPAD NSLOT                // merge-list stride 21: gcd(21,32)=1
#define SENT 0xFFFFFFFFu

// ---------------------------------------------------------------------------
// R13 = R11 structure RESTORED (separate bn/ys/head kernels, NO fences).
// R12 post-mortem: per-block __threadfence() (device scope, 8 non-coherent
// XCD L2s) stalled spline at VALUBusy 5% / 405us. Grid-wide atomic+fence
// reductions cost ~80x more than the kernel launch they replace. Kept from
// R12 (fence-free): u16 neighbor lists; float4 bn_stats loads.
// ---------------------------------------------------------------------------
__device__ inline unsigned umn(unsigned a, unsigned b) { return a < b ? a : b; }
__device__ inline unsigned umx(unsigned a, unsigned b) { return a > b ? a : b; }

__device__ inline void mat3vec(const float M[9], const float v[3], float w[3]) {
    w[0] = M[0] * v[0] + M[1] * v[1] + M[2] * v[2];
    w[1] = M[3] * v[0] + M[4] * v[1] + M[5] * v[2];
    w[2] = M[6] * v[0] + M[7] * v[1] + M[8] * v[2];
}

__device__ inline float pi3(const float M[9], float v[3]) {
    v[0] = v[1] = v[2] = 0.57735026918962576f;  // 3^-0.5 as f32
#pragma unroll
    for (int it = 0; it < 5; ++it) {
        float w[3];
        mat3vec(M, v, w);
        float nrm = sqrtf(w[0] * w[0] + w[1] * w[1] + w[2] * w[2]) + 1e-12f;
        v[0] = w[0] / nrm;
        v[1] = w[1] / nrm;
        v[2] = w[2] / nrm;
    }
    float w[3];
    mat3vec(M, v, w);
    return v[0] * w[0] + v[1] * w[1] + v[2] * w[2];
}

__global__ __launch_bounds__(KTHR, 8) void knn_kernel(
    const float* __restrict__ pos, unsigned short* __restrict__ nbr16,
    float* __restrict__ Rbuf, float* __restrict__ v3out) {
    __shared__ float smem[4 * PP];   // 64 KB arena
    float* tx = smem;                // scan: -2x  | post-merge: raw x
    float* ty = smem + PP;           // scan: -2y  | post-merge: raw y
    float* tz = smem + 2 * PP;       // scan: -2z  | post-merge: raw z
    float* tw = smem + 3 * PP;       // scan: |q|^2 (dead after scan)
    unsigned short* lnbr = (unsigned short*)(smem + 3 * PP + 2816);

    int b = blockIdx.x >> 5;          // 32 blocks per graph
    int blkInGraph = blockIdx.x & 31;
    const float* gp = pos + (size_t)b * PP * 3;
    for (int i = threadIdx.x; i < PP; i += KTHR) {
        float x = gp[i * 3 + 0];
        float y = gp[i * 3 + 1];
        float z = gp[i * 3 + 2];
        tx[i] = -2.0f * x;
        ty[i] = -2.0f * y;
        tz[i] = -2.0f * z;
        tw[i] = x * x + y * y + z * z;
    }
    __syncthreads();

    int eighth = threadIdx.x >> 7;        // 0..7 (wave-uniform)
    int pt = threadIdx.x & (PTSBLK - 1);  // 0..127
    int li = blkInGraph * PTSBLK + pt;    // local point index in graph
    float px = -0.5f * tx[li];
    float py = -0.5f * ty[li];
    float pz = -0.5f * tz[li];
    float p2 = tw[li];

    unsigned bd[NSLOT];
#pragma unroll
    for (int k = 0; k < NSLOT; k++) bd[k] = SENT;
    float worst_hat = INFINITY;

    unsigned bufk[CAP];
#pragma unroll
    for (int s = 0; s < CAP; s++) bufk[s] = SENT;

    auto flush = [&]() {
#pragma unroll
        for (int s = 0; s < CAP; s++) {
            if (!__any(bufk[s] != SENT)) break;   // monotone: FIFO fills 0..
            unsigned k = bufk[s];
#pragma unroll
            for (int i = 0; i < NSLOT; i++) {
                unsigned lo = umn(k, bd[i]);   // v_min_u32
                k = umx(k, bd[i]);             // v_max_u32
                bd[i] = lo;
            }
            bufk[s] = SENT;
        }
        unsigned wb = bd[NSLOT - 1];
        worst_hat = (wb == SENT) ? INFINITY
                                 : __uint_as_float(wb & 0xFFFFF000u) - p2;
    };

    int jbeg = eighth * CHUNK;
    for (int jj = jbeg; jj < jbeg + CHUNK; jj += 4) {
        float4 xv = *(const float4*)(tx + jj);
        float4 yv = *(const float4*)(ty + jj);
        float4 zv = *(const float4*)(tz + jj);
        float4 wv = *(const float4*)(tw + jj);
        float xa[4] = {xv.x, xv.y, xv.z, xv.w};
        float ya[4] = {yv.x, yv.y, yv.z, yv.w};
        float za[4] = {zv.x, zv.y, zv.z, zv.w};
        float wa[4] = {wv.x, wv.y, wv.z, wv.w};
#pragma unroll
        for (int u = 0; u < 4; u++) {
            float dh = fmaf(px, xa[u], fmaf(py, ya[u], fmaf(pz, za[u], wa[u])));
            if (dh < worst_hat) {
                float d = fmaxf(dh + p2, 0.0f);
                unsigned key = (__float_as_uint(d) & 0xFFFFF000u)
                               | (unsigned)(jj + u);
                bufk[6] = bufk[5];
                bufk[5] = bufk[4];
                bufk[4] = bufk[3];
                bufk[3] = bufk[2];
                bufk[2] = bufk[1];
                bufk[1] = bufk[0];
                bufk[0] = key;
            }
        }
        if (__any(bufk[3] != SENT)) flush();
    }
    flush();

    // ---- 8-way merge, two 64-point phases; emits global nbr16 + LDS lnbr ---
    __syncthreads();
    unsigned* mk = (unsigned*)smem;    // words 0..10751
    for (int h = 0; h < 2; h++) {
        if ((pt >> 6) == h) {
            int lpt = pt & 63;
#pragma unroll
            for (int k = 0; k < NSLOT; k++)
                mk[(eighth * 64 + lpt) * MPAD + k] = bd[k];
        }
        __syncthreads();
        if (threadIdx.x < 64) {
            int p = threadIdx.x;
            const unsigned* base = &mk[p * MPAD];
            int cur[SPLIT];
#pragma unroll
            for (int q = 0; q < SPLIT; q++) cur[q] = 0;
            int lpt2 = h * 64 + p;
            int gi = b * PP + blkInGraph * PTSBLK + lpt2;
#pragma unroll
            for (int t = 0; t < NSLOT; t++) {
                unsigned v[SPLIT];
#pragma unroll
                for (int q = 0; q < SPLIT; q++)
                    v[q] = base[q * 64 * MPAD + cur[q]];
                unsigned m = v[0];
#pragma unroll
                for (int q = 1; q < SPLIT; q++) m = umn(m, v[q]);
                if (t > 0) {
                    int local = (int)(m & 0xFFFu);
                    nbr16[(size_t)gi * KNN + (t - 1)] = (unsigned short)local;
                    lnbr[lpt2 * KNN + (t - 1)] = (unsigned short)local;
                }
#pragma unroll
                for (int q = 0; q < SPLIT; q++) cur[q] += (v[q] == m);
            }
        }
        __syncthreads();
    }

    // ---- re-stage RAW coords (L2-hot) for the eig tail ----
    for (int i = threadIdx.x; i < PP; i += KTHR) {
        tx[i] = gp[i * 3 + 0];
        ty[i] = gp[i * 3 + 1];
        tz[i] = gp[i * 3 + 2];
    }
    __syncthreads();

    // ---- eig tail: threads 0..127, one point each, all data in LDS ----
    if (threadIdx.x < PTSBLK) {
        int lp = threadIdx.x;
        int ng = blkInGraph * PTSBLK + lp;
        int n = b * PP + ng;
        float qx = tx[ng], qy = ty[ng], qz = tz[ng];
        const unsigned short* ln = &lnbr[lp * KNN];

        float m00 = 0.f, m01 = 0.f, m02 = 0.f, m11 = 0.f, m12 = 0.f, m22 = 0.f;
#pragma unroll
        for (int k = 0; k < LCOV; k++) {
            int id = ln[k];
            float cx = tx[id] - qx;
            float cy = ty[id] - qy;
            float cz = tz[id] - qz;
            m00 += cx * cx; m01 += cx * cy; m02 += cx * cz;
            m11 += cy * cy; m12 += cy * cz; m22 += cz * cz;
        }
        float M[9] = {m00, m01, m02, m01, m11, m12, m02, m12, m22};

        float v1[3], v2[3], v3[3];
        float l1 = pi3(M, v1);
        float M2[9];
#pragma unroll
        for (int c = 0; c < 3; c++)
#pragma unroll
            for (int d = 0; d < 3; d++)
                M2[c * 3 + d] = M[c * 3 + d] - l1 * v1[c] * v1[d];
        pi3(M2, v2);
        v3[0] = v1[1] * v2[2] - v1[2] * v2[1];
        v3[1] = v1[2] * v2[0] - v1[0] * v2[2];
        v3[2] = v1[0] * v2[1] - v1[1] * v2[0];
        {
            float nrm = sqrtf(v3[0] * v3[0] + v3[1] * v3[1] + v3[2] * v3[2]) + 1e-12f;
            v3[0] /= nrm; v3[1] /= nrm; v3[2] /= nrm;
        }

        float ssum = 0.f, mx = 0.f;
#pragma unroll
        for (int k = 0; k < KNN; k++) {
            int id = ln[k];
            float cx = tx[id] - qx;
            float cy = ty[id] - qy;
            float cz = tz[id] - qz;
            float d0 = cx * v1[0] + cy * v1[1] + cz * v1[2];
            float d1 = cx * v2[0] + cy * v2[1] + cz * v2[2];
            float d2 = cx * v3[0] + cy * v3[1] + cz * v3[2];
            ssum += d2;
            mx = fmaxf(mx, fabsf(d0));
            mx = fmaxf(mx, fabsf(d1));
            mx = fmaxf(mx, fabsf(d2));
        }
        float sgn = (ssum > 0.f) ? 1.f : ((ssum < 0.f) ? -1.f : 0.f);

        float sc = 2.0f / mx;
        float* R = Rbuf + (size_t)n * 12;
        R[0] = v1[0] * sc;  R[1] = v1[1] * sc;  R[2] = v1[2] * sc;
        R[3] = v2[0] * sc;  R[4] = v2[1] * sc;  R[5] = v2[2] * sc;
        float s2 = sgn * sc;
        R[6] = v3[0] * s2;  R[7] = v3[1] * s2;  R[8] = v3[2] * s2;
        R[9] = 0.f; R[10] = 0.f; R[11] = 0.f;

        v3out[n * 3 + 0] = v3[0];
        v3out[n * 3 + 1] = v3[1];
        v3out[n * 3 + 2] = v3[2];
    }
}

// ---------------------------------------------------------------------------
// Kernel 2: spline conv. Block = 512 threads = 16 points. (= R11, nbr16 in)
// ---------------------------------------------------------------------------
#define NPB 16
__global__ __launch_bounds__(512) void spline_kernel(
    const float* __restrict__ pos, const unsigned short* __restrict__ nbr16,
    const float* __restrict__ Rbuf, const float* __restrict__ Wsp,
    const float* __restrict__ root, const float* __restrict__ bias,
    float* __restrict__ node) {
    __shared__ float sWt[FF * 125];          // [f][flat]
    __shared__ float wbuf[NPB * KNN * 8];    // packed w' per (pt,k,s)
    for (int i = threadIdx.x; i < FF * 125; i += 512) {
        int f = i / 125;
        int j = i - f * 125;
        sWt[i] = Wsp[j * FF + f];
    }

    int tid = threadIdx.x;
    if (tid < NPB * KNN) {              // 320 phase-1 threads
        int pt = tid / KNN;
        int k = tid - pt * KNN;
        int n = blockIdx.x * NPB + pt;
        const float4* Rv = (const float4*)(Rbuf + (size_t)n * 12);
        float4 r0 = Rv[0], r1 = Rv[1], r2 = Rv[2];
        float px = pos[n * 3 + 0], py = pos[n * 3 + 1], pz = pos[n * 3 + 2];
        int id = (n & ~(PP - 1)) | (int)nbr16[(size_t)n * KNN + k];
        float cxx = pos[id * 3 + 0] - px;
        float cyy = pos[id * 3 + 1] - py;
        float czz = pos[id * 3 + 2] - pz;
        float v0 = fmaf(cxx, r0.x, fmaf(cyy, r0.y, fmaf(czz, r0.z, 2.0f)));
        float v1 = fmaf(cxx, r0.w, fmaf(cyy, r1.x, fmaf(czz, r1.y, 2.0f)));
        float v2 = fmaf(cxx, r1.z, fmaf(cyy, r1.w, fmaf(czz, r2.x, 2.0f)));
        float f0 = floorf(v0), f1 = floorf(v1), f2 = floorf(v2);
        float fr0 = v0 - f0, fr1 = v1 - f1, fr2 = v2 - f2;
        int fi0 = (int)f0, fi1 = (int)f1, fi2 = (int)f2;
        float* wdst = &wbuf[(pt * KNN + k) * 8];
#pragma unroll
        for (int s = 0; s < 8; s++) {
            int b0 = (s >> 2) & 1, b1 = (s >> 1) & 1, b2s = s & 1;
            int i0 = min(max(fi0 + b0, 0), KS - 1);
            int i1 = min(max(fi1 + b1, 0), KS - 1);
            int i2 = min(max(fi2 + b2s, 0), KS - 1);
            float w = (b0 ? fr0 : 1.f - fr0) * (b1 ? fr1 : 1.f - fr1) *
                      (b2s ? fr2 : 1.f - fr2);
            unsigned flat = (unsigned)((i0 * KS + i1) * KS + i2);
            wdst[s] = __uint_as_float((__float_as_uint(w) & ~127u) | flat);
        }
    }
    __syncthreads();

    // phase 2: thread = (pt, f)
    int pt = tid >> 5;
    int f = tid & 31;
    const float* wrow = &wbuf[pt * (KNN * 8)];
    const float* srow = &sWt[f * 125];
    float acc = 0.f;
#pragma unroll
    for (int k = 0; k < KNN; k++) {
        float4 wa = *(const float4*)&wrow[k * 8];
        float4 wb = *(const float4*)&wrow[k * 8 + 4];
        float wv[8] = {wa.x, wa.y, wa.z, wa.w, wb.x, wb.y, wb.z, wb.w};
#pragma unroll
        for (int s = 0; s < 8; s++) {
            unsigned u = __float_as_uint(wv[s]) & 127u;
            acc = fmaf(wv[s], srow[u], acc);
        }
    }
    int n = blockIdx.x * NPB + pt;
    node[(size_t)n * FF + f] = acc * (1.0f / KNN) + root[f] + bias[f];
}

// ---------------------------------------------------------------------------
// Kernel 3: batch-norm statistics — per-block PARTIALS, float4 loads.
// Stride is 0 mod 32 elements, so each float4 component sticks to one
// feature: thread t covers features 4*(t&7)+{0..3}.
// ---------------------------------------------------------------------------
#define BNBLK 256
__global__ __launch_bounds__(256) void bn_stats_kernel(const float* __restrict__ node,
                                                       float* __restrict__ sums_part) {
    __shared__ float ls[256 * 4];
    __shared__ float ls2[256 * 4];
    const float4* node4 = (const float4*)node;
    float4 s = {0.f, 0.f, 0.f, 0.f};
    float4 s2 = {0.f, 0.f, 0.f, 0.f};
    int total4 = NPTS * FF / 4;
    for (int i = blockIdx.x * 256 + threadIdx.x; i < total4; i += BNBLK * 256) {
        float4 x = node4[i];
        s.x += x.x; s.y += x.y; s.z += x.z; s.w += x.w;
        s2.x += x.x * x.x; s2.y += x.y * x.y;
        s2.z += x.z * x.z; s2.w += x.w * x.w;
    }
    int t = threadIdx.x;
    ls[t * 4 + 0] = s.x;  ls[t * 4 + 1] = s.y;
    ls[t * 4 + 2] = s.z;  ls[t * 4 + 3] = s.w;
    ls2[t * 4 + 0] = s2.x; ls2[t * 4 + 1] = s2.y;
    ls2[t * 4 + 2] = s2.z; ls2[t * 4 + 3] = s2.w;
    __syncthreads();
    if (t < 64) {
        int f = t & 31;          // feature
        int q = t >> 5;          // 0 = sum, 1 = sumsq
        int j = f >> 2, c = f & 3;   // thread residue, component
        const float* src = q ? ls2 : ls;
        float a = 0.f;
        for (int tt = j; tt < 256; tt += 8) a += src[tt * 4 + c];
        sums_part[blockIdx.x * 64 + t] = a;
    }
}

// ---------------------------------------------------------------------------
// Kernel 4: BN apply + sigmoid + reduce to ys partials (= R11).
// ---------------------------------------------------------------------------
#define YSPLIT 8
#define YCHUNK (GROUPLEN / YSPLIT)   // 16384
__global__ __launch_bounds__(256) void ys_kernel(
    const float* __restrict__ node, const float* __restrict__ v3,
    const float* __restrict__ sums_part, const float* __restrict__ gamma,
    const float* __restrict__ beta, float* __restrict__ ys_part) {
    __shared__ float stat4[256];
    __shared__ float stat[64];
    __shared__ float sa[FF], sb[FF];
    {   // parallel reduction of 256 bn partials (4 quarters x 64 columns)
        int col = threadIdx.x & 63;
        int q = threadIdx.x >> 6;
        float s = 0.f;
        for (int p2 = q * 64; p2 < (q + 1) * 64; p2++)
            s += sums_part[p2 * 64 + col];
        stat4[threadIdx.x] = s;
    }
    __syncthreads();
    if (threadIdx.x < 64) {
        stat[threadIdx.x] = stat4[threadIdx.x] + stat4[64 + threadIdx.x] +
                            stat4[128 + threadIdx.x] + stat4[192 + threadIdx.x];
    }
    __syncthreads();
    if (threadIdx.x < FF) {
        int f = threadIdx.x;
        float mu = stat[f] * (1.0f / NPTS);
        float var = stat[FF + f] * (1.0f / NPTS) - mu * mu;
        float inv = 1.0f / sqrtf(var + 1e-5f);
        sa[f] = gamma[f] * inv;
        sb[f] = beta[f] - gamma[f] * inv * mu;
    }
    __syncthreads();

    int g = blockIdx.x >> 3;
    int sub = blockIdx.x & 7;
    int t0 = g * GROUPLEN + sub * YCHUNK + threadIdx.x;
    int n = t0 / 96;
    int r0 = t0 - n * 96;
    int rj[3], fj[3], cj[3], dj[3];
    rj[0] = r0;
    rj[1] = (r0 + 64) % 96;
    rj[2] = (r0 + 32) % 96;
#pragma unroll
    for (int j = 0; j < 3; j++) {
        fj[j] = rj[j] / 3;
        cj[j] = rj[j] - fj[j] * 3;
        dj[j] = (rj[j] >= 32) ? 3 : 2;
    }
    float Sa0 = sa[fj[0]], Sb0 = sb[fj[0]];
    float Sa1 = sa[fj[1]], Sb1 = sb[fj[1]];
    float Sa2 = sa[fj[2]], Sb2 = sb[fj[2]];
    int nf = n * FF;
    int n3 = n * 3;

    float acc = 0.f;
#pragma unroll 1
    for (int tr = 0; tr < 21; tr++) {
        {
            float xb = fmaf(Sa0, node[nf + fj[0]], Sb0);
            float val = xb * v3[n3 + cj[0]];
            acc += 1.0f / (1.0f + __expf(-val));
            nf += dj[0] * FF; n3 += dj[0] * 3;
        }
        {
            float xb = fmaf(Sa1, node[nf + fj[1]], Sb1);
            float val = xb * v3[n3 + cj[1]];
            acc += 1.0f / (1.0f + __expf(-val));
            nf += dj[1] * FF; n3 += dj[1] * 3;
        }
        {
            float xb = fmaf(Sa2, node[nf + fj[2]], Sb2);
            float val = xb * v3[n3 + cj[2]];
            acc += 1.0f / (1.0f + __expf(-val));
            nf += dj[2] * FF; n3 += dj[2] * 3;
        }
    }
    {
        float xb = fmaf(Sa0, node[nf + fj[0]], Sb0);
        float val = xb * v3[n3 + cj[0]];
        acc += 1.0f / (1.0f + __expf(-val));
    }

    __shared__ float red[256];
    red[threadIdx.x] = acc;
    __syncthreads();
    if (threadIdx.x < FF) {
        float s = 0.f;
        for (int t = threadIdx.x; t < 256; t += FF) s += red[t];
        ys_part[(sub * NGROUP + g) * FF + threadIdx.x] = s * (1.0f / PP);
    }
}

// ---------------------------------------------------------------------------
// Kernel 5: MLP head; sums the 8 ys partials while loading syr. (= R11)
// ---------------------------------------------------------------------------
__global__ __launch_bounds__(256) void head_kernel(
    const float* __restrict__ ys_part, const float* __restrict__ W1,
    const float* __restrict__ b1, const float* __restrict__ W2,
    const float* __restrict__ b2, float* __restrict__ out) {
    int g = blockIdx.x;
    __shared__ float syr[FF];
    __shared__ float h[256];
    __shared__ float logits[NCLS];
    __shared__ float mstat[2];
    if (threadIdx.x < FF) {
        float s = 0.f;
#pragma unroll
        for (int sub = 0; sub < YSPLIT; sub++)
            s += ys_part[(sub * NGROUP + g) * FF + threadIdx.x];
        syr[threadIdx.x] = s;
    }
    __syncthreads();
    int j = threadIdx.x;
    float acc = b1[j];
#pragma unroll
    for (int f = 0; f < FF; f++) acc += syr[f] * W1[f * 256 + j];
    h[j] = acc > 0.f ? acc : expm1f(acc);
    __syncthreads();
    if (j < NCLS) {
        float l = b2[j];
        for (int q = 0; q < 256; q++) l += h[q] * W2[q * NCLS + j];
        logits[j] = l;
    }
    __syncthreads();
    if (j == 0) {
        float m = -INFINITY;
        for (int o = 0; o < NCLS; o++) m = fmaxf(m, logits[o]);
        float s = 0.f;
        for (int o = 0; o < NCLS; o++) s += expf(logits[o] - m);
        mstat[0] = m;
        mstat[1] = logf(s);
    }
    __syncthreads();
    if (j < NCLS) out[g * NCLS + j] = logits[j] - mstat[0] - mstat[1];
}

// ---------------------------------------------------------------------------
extern "C" void kernel_launch(void* const* d_in, const int* in_sizes, int n_in,
                              void* d_out, int out_size, void* d_ws, size_t ws_size,
                              hipStream_t stream) {
    const float* pos   = (const float*)d_in[0];
    const float* Wsp   = (const float*)d_in[1];
    const float* root  = (const float*)d_in[2];
    const float* bias  = (const float*)d_in[3];
    const float* gamma = (const float*)d_in[4];
    const float* beta  = (const float*)d_in[5];
    const float* W1    = (const float*)d_in[6];
    const float* b1    = (const float*)d_in[7];
    const float* W2    = (const float*)d_in[8];
    const float* b2    = (const float*)d_in[9];
    float* out = (float*)d_out;

    char* ws = (char*)d_ws;
    unsigned short* nbr16 = (unsigned short*)(ws);     // 32768*20*2 = 1310720
    float* sums_part = (float*)(ws + 1310720);         // 256*64*4   = 65536
    float* ys_part   = (float*)(ws + 1376256);         // 8*24*32*4  = 24576
    float* node = (float*)(ws + 2621440);              // 32768*32*4 = 4194304
    float* v3   = (float*)(ws + 6815744);              // 32768*3*4  = 393216
    float* Rbuf = (float*)(ws + 7212288);              // 32768*12*4 = 1572864

    knn_kernel<<<256, KTHR, 0, stream>>>(pos, nbr16, Rbuf, v3);
    spline_kernel<<<NPTS / NPB, 512, 0, stream>>>(pos, nbr16, Rbuf, Wsp, root,
                                                  bias, node);
    bn_stats_kernel<<<BNBLK, 256, 0, stream>>>(node, sums_part);
    ys_kernel<<<NGROUP * YSPLIT, 256, 0, stream>>>(node, v3, sums_part, gamma,
                                                   beta, ys_part);
    head_kernel<<<NGROUP, 256, 0, stream>>>(ys_part, W1, b1, W2, b2, out);
}

// Round 14
// 258.421 us; speedup vs baseline: 2.5688x; 1.0639x over previous
//
#include <hip/hip_runtime.h>
#include <hip/hip_bf16.h>
#include <math.h>

// Problem constants
#define BGR 8        // graphs
#define PP 4096      // points per graph
#define NPTS 32768   // B*P
#define KNN 20
#define LCOV 10
#define FF 32
#define KS 5
#define NCLS 40
#define NGROUP 24    // 3*B, rows of ys
#define GROUPLEN 131072  // P*F flat elements per group

// KNN tiling: 256 blocks x 1024 threads; thread = (eighth 0..7, pt 0..127)
#define SPLIT 8
#define CHUNK (PP / SPLIT)        // 512 candidates per thread
#define PTSBLK 128                // points per block
#define KTHR 1024
#define CAP 7                     // shift-register depth: 3 carry + 4/window
#define NSLOT (KNN + 1)           // 21-slot network (self-point absorbable)
#define MPAD NSLOT                // merge-list stride 21: gcd(21,32)=1
#define SENT 0xFFFFFFFFu

// ---------------------------------------------------------------------------
// R14 vs R13 (275us): tail structure only; knn untouched (VALU-saturated,
// proven insensitive to occupancy/minor trims).
//  (a) bn_stats kernel DELETED: spline blocks write per-block (sum,sumsq)
//      partials with PLAIN STORES (no atomic, no fence — kernel boundary
//      provides visibility, same mechanism R11/R13 used between kernels).
//      R12's mistake was the in-kernel last-block fence protocol, not the
//      partial writes.
//  (b) spline sWt LDS staging DELETED: phase 2 reads Wsp[flat*32+f] direct —
//      32 f-lanes hit one 128B line; Wsp (16KB) is L1-resident. LDS 26->10KB.
//  (c) ys reduces the 2048-row partials (4 accumulators, coalesced).
// ---------------------------------------------------------------------------
__device__ inline unsigned umn(unsigned a, unsigned b) { return a < b ? a : b; }
__device__ inline unsigned umx(unsigned a, unsigned b) { return a > b ? a : b; }

__device__ inline void mat3vec(const float M[9], const float v[3], float w[3]) {
    w[0] = M[0] * v[0] + M[1] * v[1] + M[2] * v[2];
    w[1] = M[3] * v[0] + M[4] * v[1] + M[5] * v[2];
    w[2] = M[6] * v[0] + M[7] * v[1] + M[8] * v[2];
}

__device__ inline float pi3(const float M[9], float v[3]) {
    v[0] = v[1] = v[2] = 0.57735026918962576f;  // 3^-0.5 as f32
#pragma unroll
    for (int it = 0; it < 5; ++it) {
        float w[3];
        mat3vec(M, v, w);
        float nrm = sqrtf(w[0] * w[0] + w[1] * w[1] + w[2] * w[2]) + 1e-12f;
        v[0] = w[0] / nrm;
        v[1] = w[1] / nrm;
        v[2] = w[2] / nrm;
    }
    float w[3];
    mat3vec(M, v, w);
    return v[0] * w[0] + v[1] * w[1] + v[2] * w[2];
}

__global__ __launch_bounds__(KTHR, 8) void knn_kernel(
    const float* __restrict__ pos, unsigned short* __restrict__ nbr16,
    float* __restrict__ Rbuf, float* __restrict__ v3out) {
    __shared__ float smem[4 * PP];   // 64 KB arena
    float* tx = smem;                // scan: -2x  | post-merge: raw x
    float* ty = smem + PP;           // scan: -2y  | post-merge: raw y
    float* tz = smem + 2 * PP;       // scan: -2z  | post-merge: raw z
    float* tw = smem + 3 * PP;       // scan: |q|^2 (dead after scan)
    unsigned short* lnbr = (unsigned short*)(smem + 3 * PP + 2816);

    int b = blockIdx.x >> 5;          // 32 blocks per graph
    int blkInGraph = blockIdx.x & 31;
    const float* gp = pos + (size_t)b * PP * 3;
    for (int i = threadIdx.x; i < PP; i += KTHR) {
        float x = gp[i * 3 + 0];
        float y = gp[i * 3 + 1];
        float z = gp[i * 3 + 2];
        tx[i] = -2.0f * x;
        ty[i] = -2.0f * y;
        tz[i] = -2.0f * z;
        tw[i] = x * x + y * y + z * z;
    }
    __syncthreads();

    int eighth = threadIdx.x >> 7;        // 0..7 (wave-uniform)
    int pt = threadIdx.x & (PTSBLK - 1);  // 0..127
    int li = blkInGraph * PTSBLK + pt;    // local point index in graph
    float px = -0.5f * tx[li];
    float py = -0.5f * ty[li];
    float pz = -0.5f * tz[li];
    float p2 = tw[li];

    unsigned bd[NSLOT];
#pragma unroll
    for (int k = 0; k < NSLOT; k++) bd[k] = SENT;
    float worst_hat = INFINITY;

    unsigned bufk[CAP];
#pragma unroll
    for (int s = 0; s < CAP; s++) bufk[s] = SENT;

    auto flush = [&]() {
#pragma unroll
        for (int s = 0; s < CAP; s++) {
            if (!__any(bufk[s] != SENT)) break;   // monotone: FIFO fills 0..
            unsigned k = bufk[s];
#pragma unroll
            for (int i = 0; i < NSLOT; i++) {
                unsigned lo = umn(k, bd[i]);   // v_min_u32
                k = umx(k, bd[i]);             // v_max_u32
                bd[i] = lo;
            }
            bufk[s] = SENT;
        }
        unsigned wb = bd[NSLOT - 1];
        worst_hat = (wb == SENT) ? INFINITY
                                 : __uint_as_float(wb & 0xFFFFF000u) - p2;
    };

    int jbeg = eighth * CHUNK;
    for (int jj = jbeg; jj < jbeg + CHUNK; jj += 4) {
        float4 xv = *(const float4*)(tx + jj);
        float4 yv = *(const float4*)(ty + jj);
        float4 zv = *(const float4*)(tz + jj);
        float4 wv = *(const float4*)(tw + jj);
        float xa[4] = {xv.x, xv.y, xv.z, xv.w};
        float ya[4] = {yv.x, yv.y, yv.z, yv.w};
        float za[4] = {zv.x, zv.y, zv.z, zv.w};
        float wa[4] = {wv.x, wv.y, wv.z, wv.w};
#pragma unroll
        for (int u = 0; u < 4; u++) {
            float dh = fmaf(px, xa[u], fmaf(py, ya[u], fmaf(pz, za[u], wa[u])));
            if (dh < worst_hat) {
                float d = fmaxf(dh + p2, 0.0f);
                unsigned key = (__float_as_uint(d) & 0xFFFFF000u)
                               | (unsigned)(jj + u);
                bufk[6] = bufk[5];
                bufk[5] = bufk[4];
                bufk[4] = bufk[3];
                bufk[3] = bufk[2];
                bufk[2] = bufk[1];
                bufk[1] = bufk[0];
                bufk[0] = key;
            }
        }
        if (__any(bufk[3] != SENT)) flush();
    }
    flush();

    // ---- 8-way merge, two 64-point phases; emits global nbr16 + LDS lnbr ---
    __syncthreads();
    unsigned* mk = (unsigned*)smem;    // words 0..10751
    for (int h = 0; h < 2; h++) {
        if ((pt >> 6) == h) {
            int lpt = pt & 63;
#pragma unroll
            for (int k = 0; k < NSLOT; k++)
                mk[(eighth * 64 + lpt) * MPAD + k] = bd[k];
        }
        __syncthreads();
        if (threadIdx.x < 64) {
            int p = threadIdx.x;
            const unsigned* base = &mk[p * MPAD];
            int cur[SPLIT];
#pragma unroll
            for (int q = 0; q < SPLIT; q++) cur[q] = 0;
            int lpt2 = h * 64 + p;
            int gi = b * PP + blkInGraph * PTSBLK + lpt2;
#pragma unroll
            for (int t = 0; t < NSLOT; t++) {
                unsigned v[SPLIT];
#pragma unroll
                for (int q = 0; q < SPLIT; q++)
                    v[q] = base[q * 64 * MPAD + cur[q]];
                unsigned m = v[0];
#pragma unroll
                for (int q = 1; q < SPLIT; q++) m = umn(m, v[q]);
                if (t > 0) {
                    int local = (int)(m & 0xFFFu);
                    nbr16[(size_t)gi * KNN + (t - 1)] = (unsigned short)local;
                    lnbr[lpt2 * KNN + (t - 1)] = (unsigned short)local;
                }
#pragma unroll
                for (int q = 0; q < SPLIT; q++) cur[q] += (v[q] == m);
            }
        }
        __syncthreads();
    }

    // ---- re-stage RAW coords (L2-hot) for the eig tail ----
    for (int i = threadIdx.x; i < PP; i += KTHR) {
        tx[i] = gp[i * 3 + 0];
        ty[i] = gp[i * 3 + 1];
        tz[i] = gp[i * 3 + 2];
    }
    __syncthreads();

    // ---- eig tail: threads 0..127, one point each, all data in LDS ----
    if (threadIdx.x < PTSBLK) {
        int lp = threadIdx.x;
        int ng = blkInGraph * PTSBLK + lp;
        int n = b * PP + ng;
        float qx = tx[ng], qy = ty[ng], qz = tz[ng];
        const unsigned short* ln = &lnbr[lp * KNN];

        float m00 = 0.f, m01 = 0.f, m02 = 0.f, m11 = 0.f, m12 = 0.f, m22 = 0.f;
#pragma unroll
        for (int k = 0; k < LCOV; k++) {
            int id = ln[k];
            float cx = tx[id] - qx;
            float cy = ty[id] - qy;
            float cz = tz[id] - qz;
            m00 += cx * cx; m01 += cx * cy; m02 += cx * cz;
            m11 += cy * cy; m12 += cy * cz; m22 += cz * cz;
        }
        float M[9] = {m00, m01, m02, m01, m11, m12, m02, m12, m22};

        float v1[3], v2[3], v3[3];
        float l1 = pi3(M, v1);
        float M2[9];
#pragma unroll
        for (int c = 0; c < 3; c++)
#pragma unroll
            for (int d = 0; d < 3; d++)
                M2[c * 3 + d] = M[c * 3 + d] - l1 * v1[c] * v1[d];
        pi3(M2, v2);
        v3[0] = v1[1] * v2[2] - v1[2] * v2[1];
        v3[1] = v1[2] * v2[0] - v1[0] * v2[2];
        v3[2] = v1[0] * v2[1] - v1[1] * v2[0];
        {
            float nrm = sqrtf(v3[0] * v3[0] + v3[1] * v3[1] + v3[2] * v3[2]) + 1e-12f;
            v3[0] /= nrm; v3[1] /= nrm; v3[2] /= nrm;
        }

        float ssum = 0.f, mx = 0.f;
#pragma unroll
        for (int k = 0; k < KNN; k++) {
            int id = ln[k];
            float cx = tx[id] - qx;
            float cy = ty[id] - qy;
            float cz = tz[id] - qz;
            float d0 = cx * v1[0] + cy * v1[1] + cz * v1[2];
            float d1 = cx * v2[0] + cy * v2[1] + cz * v2[2];
            float d2 = cx * v3[0] + cy * v3[1] + cz * v3[2];
            ssum += d2;
            mx = fmaxf(mx, fabsf(d0));
            mx = fmaxf(mx, fabsf(d1));
            mx = fmaxf(mx, fabsf(d2));
        }
        float sgn = (ssum > 0.f) ? 1.f : ((ssum < 0.f) ? -1.f : 0.f);

        float sc = 2.0f / mx;
        float* R = Rbuf + (size_t)n * 12;
        R[0] = v1[0] * sc;  R[1] = v1[1] * sc;  R[2] = v1[2] * sc;
        R[3] = v2[0] * sc;  R[4] = v2[1] * sc;  R[5] = v2[2] * sc;
        float s2 = sgn * sc;
        R[6] = v3[0] * s2;  R[7] = v3[1] * s2;  R[8] = v3[2] * s2;
        R[9] = 0.f; R[10] = 0.f; R[11] = 0.f;

        v3out[n * 3 + 0] = v3[0];
        v3out[n * 3 + 1] = v3[1];
        v3out[n * 3 + 2] = v3[2];
    }
}

// ---------------------------------------------------------------------------
// Kernel 2: spline conv + per-block bn partials (fence-free).
// Phase 2 reads Wsp DIRECTLY (flat*32+f: 32 f-lanes = one 128B line,
// Wsp 16KB L1-resident). After phase 2, block reduces its 512 node values
// to (sum|sumsq)[32] and plain-stores to sums_part[block][64].
// ---------------------------------------------------------------------------
#define NPB 16
#define SPLBLKS (NPTS / NPB)   // 2048
__global__ __launch_bounds__(512) void spline_kernel(
    const float* __restrict__ pos, const unsigned short* __restrict__ nbr16,
    const float* __restrict__ Rbuf, const float* __restrict__ Wsp,
    const float* __restrict__ root, const float* __restrict__ bias,
    float* __restrict__ node, float* __restrict__ sums_part) {
    __shared__ float wbuf[NPB * KNN * 8];    // packed w' per (pt,k,s); reused

    int tid = threadIdx.x;
    if (tid < NPB * KNN) {              // 320 phase-1 threads
        int pt = tid / KNN;
        int k = tid - pt * KNN;
        int n = blockIdx.x * NPB + pt;
        const float4* Rv = (const float4*)(Rbuf + (size_t)n * 12);
        float4 r0 = Rv[0], r1 = Rv[1], r2 = Rv[2];
        float px = pos[n * 3 + 0], py = pos[n * 3 + 1], pz = pos[n * 3 + 2];
        int id = (n & ~(PP - 1)) | (int)nbr16[(size_t)n * KNN + k];
        float cxx = pos[id * 3 + 0] - px;
        float cyy = pos[id * 3 + 1] - py;
        float czz = pos[id * 3 + 2] - pz;
        float v0 = fmaf(cxx, r0.x, fmaf(cyy, r0.y, fmaf(czz, r0.z, 2.0f)));
        float v1 = fmaf(cxx, r0.w, fmaf(cyy, r1.x, fmaf(czz, r1.y, 2.0f)));
        float v2 = fmaf(cxx, r1.z, fmaf(cyy, r1.w, fmaf(czz, r2.x, 2.0f)));
        float f0 = floorf(v0), f1 = floorf(v1), f2 = floorf(v2);
        float fr0 = v0 - f0, fr1 = v1 - f1, fr2 = v2 - f2;
        int fi0 = (int)f0, fi1 = (int)f1, fi2 = (int)f2;
        float* wdst = &wbuf[(pt * KNN + k) * 8];
#pragma unroll
        for (int s = 0; s < 8; s++) {
            int b0 = (s >> 2) & 1, b1 = (s >> 1) & 1, b2s = s & 1;
            int i0 = min(max(fi0 + b0, 0), KS - 1);
            int i1 = min(max(fi1 + b1, 0), KS - 1);
            int i2 = min(max(fi2 + b2s, 0), KS - 1);
            float w = (b0 ? fr0 : 1.f - fr0) * (b1 ? fr1 : 1.f - fr1) *
                      (b2s ? fr2 : 1.f - fr2);
            unsigned flat = (unsigned)((i0 * KS + i1) * KS + i2);
            wdst[s] = __uint_as_float((__float_as_uint(w) & ~127u) | flat);
        }
    }
    __syncthreads();

    // phase 2: thread = (pt, f); Wsp read direct (L1-resident, coalesced)
    int pt = tid >> 5;
    int f = tid & 31;
    const float* wrow = &wbuf[pt * (KNN * 8)];
    float acc = 0.f;
#pragma unroll
    for (int k = 0; k < KNN; k++) {
        float4 wa = *(const float4*)&wrow[k * 8];
        float4 wb = *(const float4*)&wrow[k * 8 + 4];
        float wv[8] = {wa.x, wa.y, wa.z, wa.w, wb.x, wb.y, wb.z, wb.w};
#pragma unroll
        for (int s = 0; s < 8; s++) {
            unsigned u = __float_as_uint(wv[s]) & 127u;
            acc = fmaf(wv[s], Wsp[u * FF + f], acc);
        }
    }
    int n = blockIdx.x * NPB + pt;
    float val = acc * (1.0f / KNN) + root[f] + bias[f];
    node[(size_t)n * FF + f] = val;

    // ---- per-block bn partial (plain stores; kernel boundary = sync) ----
    __syncthreads();                 // wbuf reads done; safe to reuse
    wbuf[tid] = val;
    wbuf[512 + tid] = val * val;
    __syncthreads();
    if (tid < 64) {
        int ff = tid & 31;
        int off = (tid >> 5) * 512;  // 0 = sum, 512 = sumsq
        float s = 0.f;
#pragma unroll
        for (int p = 0; p < NPB; p++) s += wbuf[off + p * 32 + ff];
        sums_part[(size_t)blockIdx.x * 64 + tid] = s;
    }
}

// ---------------------------------------------------------------------------
// Kernel 3: BN apply + sigmoid + reduce to ys partials. Stats stage reduces
// the 2048 spline-block partials (coalesced, 4 accumulators).
// ---------------------------------------------------------------------------
#define YSPLIT 8
#define YCHUNK (GROUPLEN / YSPLIT)   // 16384
__global__ __launch_bounds__(256) void ys_kernel(
    const float* __restrict__ node, const float* __restrict__ v3,
    const float* __restrict__ sums_part, const float* __restrict__ gamma,
    const float* __restrict__ beta, float* __restrict__ ys_part) {
    __shared__ float stat4[256];
    __shared__ float stat[64];
    __shared__ float sa[FF], sb[FF];
    {   // reduce 2048 partials: 4 quarters x 64 columns, 4 accumulators
        int col = threadIdx.x & 63;
        int q = threadIdx.x >> 6;
        float s0 = 0.f, s1 = 0.f, s2 = 0.f, s3 = 0.f;
        for (int p = q * 512; p < (q + 1) * 512; p += 4) {
            s0 += sums_part[(p + 0) * 64 + col];
            s1 += sums_part[(p + 1) * 64 + col];
            s2 += sums_part[(p + 2) * 64 + col];
            s3 += sums_part[(p + 3) * 64 + col];
        }
        stat4[threadIdx.x] = (s0 + s1) + (s2 + s3);
    }
    __syncthreads();
    if (threadIdx.x < 64) {
        stat[threadIdx.x] = stat4[threadIdx.x] + stat4[64 + threadIdx.x] +
                            stat4[128 + threadIdx.x] + stat4[192 + threadIdx.x];
    }
    __syncthreads();
    if (threadIdx.x < FF) {
        int f = threadIdx.x;
        float mu = stat[f] * (1.0f / NPTS);
        float var = stat[FF + f] * (1.0f / NPTS) - mu * mu;
        float inv = 1.0f / sqrtf(var + 1e-5f);
        sa[f] = gamma[f] * inv;
        sb[f] = beta[f] - gamma[f] * inv * mu;
    }
    __syncthreads();

    int g = blockIdx.x >> 3;
    int sub = blockIdx.x & 7;
    int t0 = g * GROUPLEN + sub * YCHUNK + threadIdx.x;
    int n = t0 / 96;
    int r0 = t0 - n * 96;
    int rj[3], fj[3], cj[3], dj[3];
    rj[0] = r0;
    rj[1] = (r0 + 64) % 96;
    rj[2] = (r0 + 32) % 96;
#pragma unroll
    for (int j = 0; j < 3; j++) {
        fj[j] = rj[j] / 3;
        cj[j] = rj[j] - fj[j] * 3;
        dj[j] = (rj[j] >= 32) ? 3 : 2;
    }
    float Sa0 = sa[fj[0]], Sb0 = sb[fj[0]];
    float Sa1 = sa[fj[1]], Sb1 = sb[fj[1]];
    float Sa2 = sa[fj[2]], Sb2 = sb[fj[2]];
    int nf = n * FF;
    int n3 = n * 3;

    float acc = 0.f;
#pragma unroll 1
    for (int tr = 0; tr < 21; tr++) {
        {
            float xb = fmaf(Sa0, node[nf + fj[0]], Sb0);
            float val = xb * v3[n3 + cj[0]];
            acc += 1.0f / (1.0f + __expf(-val));
            nf += dj[0] * FF; n3 += dj[0] * 3;
        }
        {
            float xb = fmaf(Sa1, node[nf + fj[1]], Sb1);
            float val = xb * v3[n3 + cj[1]];
            acc += 1.0f / (1.0f + __expf(-val));
            nf += dj[1] * FF; n3 += dj[1] * 3;
        }
        {
            float xb = fmaf(Sa2, node[nf + fj[2]], Sb2);
            float val = xb * v3[n3 + cj[2]];
            acc += 1.0f / (1.0f + __expf(-val));
            nf += dj[2] * FF; n3 += dj[2] * 3;
        }
    }
    {
        float xb = fmaf(Sa0, node[nf + fj[0]], Sb0);
        float val = xb * v3[n3 + cj[0]];
        acc += 1.0f / (1.0f + __expf(-val));
    }

    __shared__ float red[256];
    red[threadIdx.x] = acc;
    __syncthreads();
    if (threadIdx.x < FF) {
        float s = 0.f;
        for (int t = threadIdx.x; t < 256; t += FF) s += red[t];
        ys_part[(sub * NGROUP + g) * FF + threadIdx.x] = s * (1.0f / PP);
    }
}

// ---------------------------------------------------------------------------
// Kernel 4: MLP head; sums the 8 ys partials while loading syr.
// ---------------------------------------------------------------------------
__global__ __launch_bounds__(256) void head_kernel(
    const float* __restrict__ ys_part, const float* __restrict__ W1,
    const float* __restrict__ b1, const float* __restrict__ W2,
    const float* __restrict__ b2, float* __restrict__ out) {
    int g = blockIdx.x;
    __shared__ float syr[FF];
    __shared__ float h[256];
    __shared__ float logits[NCLS];
    __shared__ float mstat[2];
    if (threadIdx.x < FF) {
        float s = 0.f;
#pragma unroll
        for (int sub = 0; sub < YSPLIT; sub++)
            s += ys_part[(sub * NGROUP + g) * FF + threadIdx.x];
        syr[threadIdx.x] = s;
    }
    __syncthreads();
    int j = threadIdx.x;
    float acc = b1[j];
#pragma unroll
    for (int f = 0; f < FF; f++) acc += syr[f] * W1[f * 256 + j];
    h[j] = acc > 0.f ? acc : expm1f(acc);
    __syncthreads();
    if (j < NCLS) {
        float l = b2[j];
        for (int q = 0; q < 256; q++) l += h[q] * W2[q * NCLS + j];
        logits[j] = l;
    }
    __syncthreads();
    if (j == 0) {
        float m = -INFINITY;
        for (int o = 0; o < NCLS; o++) m = fmaxf(m, logits[o]);
        float s = 0.f;
        for (int o = 0; o < NCLS; o++) s += expf(logits[o] - m);
        mstat[0] = m;
        mstat[1] = logf(s);
    }
    __syncthreads();
    if (j < NCLS) out[g * NCLS + j] = logits[j] - mstat[0] - mstat[1];
}

// ---------------------------------------------------------------------------
extern "C" void kernel_launch(void* const* d_in, const int* in_sizes, int n_in,
                              void* d_out, int out_size, void* d_ws, size_t ws_size,
                              hipStream_t stream) {
    const float* pos   = (const float*)d_in[0];
    const float* Wsp   = (const float*)d_in[1];
    const float* root  = (const float*)d_in[2];
    const float* bias  = (const float*)d_in[3];
    const float* gamma = (const float*)d_in[4];
    const float* beta  = (const float*)d_in[5];
    const float* W1    = (const float*)d_in[6];
    const float* b1    = (const float*)d_in[7];
    const float* W2    = (const float*)d_in[8];
    const float* b2    = (const float*)d_in[9];
    float* out = (float*)d_out;

    char* ws = (char*)d_ws;
    unsigned short* nbr16 = (unsigned short*)(ws);     // 32768*20*2 = 1310720
    float* sums_part = (float*)(ws + 1310720);         // 2048*64*4  = 524288
    float* ys_part   = (float*)(ws + 1835008);         // 8*24*32*4  = 24576
    float* node = (float*)(ws + 2621440);              // 32768*32*4 = 4194304
    float* v3   = (float*)(ws + 6815744);              // 32768*3*4  = 393216
    float* Rbuf = (float*)(ws + 7212288);              // 32768*12*4 = 1572864

    knn_kernel<<<256, KTHR, 0, stream>>>(pos, nbr16, Rbuf, v3);
    spline_kernel<<<SPLBLKS, 512, 0, stream>>>(pos, nbr16, Rbuf, Wsp, root,
                                               bias, node, sums_part);
    ys_kernel<<<NGROUP * YSPLIT, 256, 0, stream>>>(node, v3, sums_part, gamma,
                                                   beta, ys_part);
    head_kernel<<<NGROUP, 256, 0, stream>>>(ys_part, W1, b1, W2, b2, out);
}